// Round 13
// baseline (505.546 us; speedup 1.0000x reference)
//
#include <hip/hip_runtime.h>
#include <hip/hip_bf16.h>
#include <stdint.h>

#define NROWS 8192
#define DIM 512

typedef short bf16x8 __attribute__((ext_vector_type(8)));
typedef float f32x4 __attribute__((ext_vector_type(4)));

__device__ __forceinline__ unsigned short f2bf(float f) {
    union { float f; uint32_t u; } c; c.f = f;
    uint32_t u = c.u;
    return (unsigned short)((u + 0x7FFFu + ((u >> 16) & 1u)) >> 16);
}

__device__ __forceinline__ void gload16(const unsigned short* g, unsigned short* l) {
    __builtin_amdgcn_global_load_lds((const __attribute__((address_space(1))) void*)g,
                                     (__attribute__((address_space(3))) void*)l,
                                     16, 0, 0);
}

// ---------------- Kernel 1: L2-normalize rows -> bf16; zero the scalar output --------
__global__ __launch_bounds__(256) void knorm(const float* __restrict__ in,
                                             unsigned short* __restrict__ out,
                                             float* __restrict__ loss_out) {
    if (blockIdx.x == 0 && threadIdx.x == 0) loss_out[0] = 0.0f;
    const int row  = (blockIdx.x << 2) + (threadIdx.x >> 6);
    const int lane = threadIdx.x & 63;
    const float4* src = (const float4*)(in + (size_t)row * DIM);
    float4 a = src[lane];
    float4 b = src[lane + 64];
    float ss = a.x*a.x + a.y*a.y + a.z*a.z + a.w*a.w
             + b.x*b.x + b.y*b.y + b.z*b.z + b.w*b.w;
    #pragma unroll
    for (int m = 1; m < 64; m <<= 1) ss += __shfl_xor(ss, m);
    const float inv = 1.0f / sqrtf(ss);
    ushort4* dst = (ushort4*)(out + (size_t)row * DIM);
    ushort4 o;
    o.x = f2bf(a.x*inv); o.y = f2bf(a.y*inv); o.z = f2bf(a.z*inv); o.w = f2bf(a.w*inv);
    dst[lane] = o;
    o.x = f2bf(b.x*inv); o.y = f2bf(b.y*inv); o.z = f2bf(b.z*inv); o.w = f2bf(b.w*inv);
    dst[lane + 64] = o;
}

// ---------------- Kernel 2: R9 main loop + atomic-free partial-sum epilogue -----------
// IDENTICAL to R9 (measured best: 56.4us kgemm, 628 TF, 0 conflicts, FETCH 19.4 MB)
// except __launch_bounds__(1024, 8): guarantees 8 waves/EU residency = 2 blocks/CU
// (LDS 2x64KB <= 160KB; regs 64 VGPR + 64 AGPR = 128/lane <= pool/8-waves), so a
// second block's waves fill this block's barrier/vmcnt stalls. NO device fences
// (R11 lesson: __threadfence => L2 writeback storm on non-coherent XCD L2s).
__global__ __launch_bounds__(1024, 8) void kgemm(const unsigned short* __restrict__ E,
                                                 float* __restrict__ part,
                                                 float* __restrict__ pospart) {
    __shared__ unsigned short lds[2][2][256 * 32];

    const int tid = threadIdx.x;
    const int w = tid >> 6;
    const int l = tid & 63;

    // ---- block id -> (bi, bj): supertile triangle decode ----
    const int lin = (int)((blockIdx.x & 7) * 66 + (blockIdx.x >> 3));
    int rem = lin;
    int SI = -1, SJ = -1;
    #pragma unroll
    for (int s = 0; s < 10; s++) {
        constexpr int si_t[10] = {0,0,0,0,1,1,1,2,2,3};
        constexpr int sj_t[10] = {0,1,2,3,1,2,3,2,3,3};
        const int sz = (si_t[s] == sj_t[s]) ? 36 : 64;
        if (SI < 0) {
            if (rem < sz) { SI = si_t[s]; SJ = sj_t[s]; }
            else rem -= sz;
        }
    }
    int bi, bj;
    if (SI == SJ) {
        int x = 0;
        while (rem >= 8 - x) { rem -= 8 - x; x++; }
        bi = (SI << 3) + x; bj = (SI << 3) + x + rem;
    } else {
        bi = (SI << 3) + (rem >> 3);
        bj = (SJ << 3) + (rem & 7);
    }

    const int brow = bi << 8;
    const int bcol = bj << 8;
    const int wr = (w >> 2) << 6;
    const int wc = (w & 3) << 6;

    f32x4 acc[4][4];
    #pragma unroll
    for (int i = 0; i < 4; i++)
        #pragma unroll
        for (int j = 0; j < 4; j++) acc[i][j] = (f32x4)0.0f;

    const int g_src = (l & 3) ^ ((l >> 3) & 3);
    const int r_st  = (w << 4) + (l >> 2);

    auto STAGE = [&](int buf, int kt) {
        const size_t colb = (size_t)((kt << 5) + (g_src << 3));
        gload16(E + (size_t)(brow + r_st) * DIM + colb, &lds[buf][0][w << 9]);
        gload16(E + (size_t)(bcol + r_st) * DIM + colb, &lds[buf][1][w << 9]);
    };

    const int sgk = (((l >> 4) ^ ((l >> 1) & 3)) << 3);

    auto COMPUTE = [&](int buf) {
        const unsigned short* sA = lds[buf][0];
        const unsigned short* sB = lds[buf][1];
        bf16x8 aF[4], bF[4];
        #pragma unroll
        for (int mi = 0; mi < 4; mi++) {
            const int rr = wr + (mi << 4) + (l & 15);
            aF[mi] = *(const bf16x8*)&sA[(rr << 5) + sgk];
        }
        #pragma unroll
        for (int ni = 0; ni < 4; ni++) {
            const int rr = wc + (ni << 4) + (l & 15);
            bF[ni] = *(const bf16x8*)&sB[(rr << 5) + sgk];
        }
        #pragma unroll
        for (int mi = 0; mi < 4; mi++)
            #pragma unroll
            for (int ni = 0; ni < 4; ni++)
                acc[mi][ni] = __builtin_amdgcn_mfma_f32_16x16x32_bf16(
                    aF[mi], bF[ni], acc[mi][ni], 0, 0, 0);
    };

    STAGE(0, 0);
    #pragma unroll
    for (int kt = 0; kt < 16; kt++) {
        if (kt > 0) __builtin_amdgcn_s_barrier();
        if (kt < 15) {
            STAGE((kt + 1) & 1, kt + 1);
            asm volatile("s_waitcnt vmcnt(2)" ::: "memory");
        } else {
            asm volatile("s_waitcnt vmcnt(0)" ::: "memory");
        }
        __builtin_amdgcn_sched_barrier(0);
        __builtin_amdgcn_s_barrier();
        COMPUTE(kt & 1);
    }

    // ---- epilogue: exp(10*dot - 10), classify, LDS assemble, streaming store ----
    float* lds_row = (float*)&lds[0][0][0];       // [4][256]
    float* lds_col = lds_row + 1024;              // [4][256]
    float* lds_pos = lds_row + 2048;              // [4][256]

    __syncthreads();   // all COMPUTE reads done before LDS reuse

    if (bi == bj) {
        #pragma unroll
        for (int mi = 0; mi < 4; mi++) {
            #pragma unroll
            for (int r = 0; r < 4; r++) {
                const int lrow = wr + (mi << 4) + ((l >> 4) << 2) + r;
                const int gi = brow + lrow;
                float p = 0.0f, n = 0.0f;
                #pragma unroll
                for (int ni = 0; ni < 4; ni++) {
                    const int gj = bcol + wc + (ni << 4) + (l & 15);
                    const float e = __expf(fmaf(acc[mi][ni][r], 10.0f, -10.0f));
                    if (gi == gj) {
                    } else if ((gi >> 2) == (gj >> 2)) {
                        p += e;
                    } else {
                        n += e;
                    }
                }
                #pragma unroll
                for (int m = 1; m < 16; m <<= 1) {
                    n += __shfl_xor(n, m);
                    p += __shfl_xor(p, m);
                }
                if ((l & 15) == 0) {
                    lds_row[((w & 3) << 8) + lrow] = n;
                    lds_pos[((w & 3) << 8) + lrow] = p;
                }
            }
        }
    } else {
        float c[4] = {0.0f, 0.0f, 0.0f, 0.0f};
        #pragma unroll
        for (int mi = 0; mi < 4; mi++) {
            #pragma unroll
            for (int r = 0; r < 4; r++) {
                const int lrow = wr + (mi << 4) + ((l >> 4) << 2) + r;
                float n = 0.0f;
                #pragma unroll
                for (int ni = 0; ni < 4; ni++) {
                    const float e = __expf(fmaf(acc[mi][ni][r], 10.0f, -10.0f));
                    n += e;
                    c[ni] += e;
                }
                #pragma unroll
                for (int m = 1; m < 16; m <<= 1) n += __shfl_xor(n, m);
                if ((l & 15) == 0) lds_row[((w & 3) << 8) + lrow] = n;
            }
        }
        #pragma unroll
        for (int ni = 0; ni < 4; ni++) {
            c[ni] += __shfl_xor(c[ni], 16);
            c[ni] += __shfl_xor(c[ni], 32);
            if ((l >> 4) == 0)
                lds_col[((w >> 2) << 8) + wc + (ni << 4) + l] = c[ni];
        }
    }
    __syncthreads();

    if (tid < 256) {
        const float s = lds_row[tid] + lds_row[256 + tid]
                      + lds_row[512 + tid] + lds_row[768 + tid];
        part[((size_t)lin << 9) + tid] = s;
    } else if (tid < 512) {
        if (bi != bj) {
            const int cc = tid - 256;
            const float s = lds_col[cc] + lds_col[256 + cc]
                          + lds_col[512 + cc] + lds_col[768 + cc];
            part[((size_t)lin << 9) + 256 + cc] = s;
        }
    } else if (tid < 768) {
        if (bi == bj) {
            const int rr = tid - 512;
            const float s = lds_pos[rr] + lds_pos[256 + rr]
                          + lds_pos[512 + rr] + lds_pos[768 + rr];
            pospart[(bi << 8) + rr] = s;
        }
    }
}

// ---------------- Kernel 3: gather partials, compute loss, reduce ----------------
__global__ __launch_bounds__(256) void kred(const float* __restrict__ part,
                                            const float* __restrict__ pospart,
                                            float* __restrict__ out) {
    const int T = blockIdx.x;
    const int r = threadIdx.x;

    auto linof = [](int a, int b) {   // a <= b, 0..31
        constexpr int base[4][4] = {{0, 36, 100, 164},
                                    {0, 228, 264, 328},
                                    {0, 0, 392, 428},
                                    {0, 0, 0, 492}};
        const int SI = a >> 3, SJ = b >> 3, x = a & 7, y = b & 7;
        int inner;
        if (SI == SJ) inner = (x << 3) - ((x * (x - 1)) >> 1) + (y - x);
        else          inner = (x << 3) + y;
        return base[SI][SJ] + inner;
    };

    float n = 0.0f;
    for (int bj = T; bj < 32; bj++)
        n += part[((size_t)linof(T, bj) << 9) + r];
    for (int bi = 0; bi < T; bi++)
        n += part[((size_t)linof(bi, T) << 9) + 256 + r];
    const float p = pospart[(T << 8) + r];

    float s = __logf(p + n + 1e-8f) - __logf(p);
    #pragma unroll
    for (int m = 1; m < 64; m <<= 1) s += __shfl_xor(s, m);
    __shared__ float red[4];
    if ((r & 63) == 0) red[r >> 6] = s;
    __syncthreads();
    if (r == 0)
        atomicAdd(out, (red[0] + red[1] + red[2] + red[3]) * (1.0f / (float)NROWS));
}

extern "C" void kernel_launch(void* const* d_in, const int* in_sizes, int n_in,
                              void* d_out, int out_size, void* d_ws, size_t ws_size,
                              hipStream_t stream) {
    (void)in_sizes; (void)n_in; (void)out_size; (void)ws_size;
    const float* emb = (const float*)d_in[0];
    unsigned short* En = (unsigned short*)d_ws;                          // 8 MB bf16
    float* pospart = (float*)((char*)d_ws + (size_t)NROWS * DIM * 2);    // 32 KB
    float* part    = pospart + 32 * 256;                                 // 1.05 MB

    knorm<<<NROWS / 4, 256, 0, stream>>>(emb, En, (float*)d_out);
    kgemm<<<528, 1024, 0, stream>>>(En, part, pospart);
    kred<<<32, 256, 0, stream>>>(part, pospart, (float*)d_out);
}

// Round 14
// 77.476 us; speedup vs baseline: 6.5252x; 6.5252x over previous
//
#include <hip/hip_runtime.h>
#include <hip/hip_bf16.h>
#include <stdint.h>

#define NROWS 8192
#define DIM 512

typedef short bf16x8 __attribute__((ext_vector_type(8)));
typedef float f32x4 __attribute__((ext_vector_type(4)));

__device__ __forceinline__ unsigned short f2bf(float f) {
    union { float f; uint32_t u; } c; c.f = f;
    uint32_t u = c.u;
    return (unsigned short)((u + 0x7FFFu + ((u >> 16) & 1u)) >> 16);
}

__device__ __forceinline__ void gload16(const unsigned short* g, unsigned short* l) {
    __builtin_amdgcn_global_load_lds((const __attribute__((address_space(1))) void*)g,
                                     (__attribute__((address_space(3))) void*)l,
                                     16, 0, 0);
}

// ---------------- Kernel 1: L2-normalize rows -> bf16; zero the scalar output --------
__global__ __launch_bounds__(256) void knorm(const float* __restrict__ in,
                                             unsigned short* __restrict__ out,
                                             float* __restrict__ loss_out) {
    if (blockIdx.x == 0 && threadIdx.x == 0) loss_out[0] = 0.0f;
    const int row  = (blockIdx.x << 2) + (threadIdx.x >> 6);
    const int lane = threadIdx.x & 63;
    const float4* src = (const float4*)(in + (size_t)row * DIM);
    float4 a = src[lane];
    float4 b = src[lane + 64];
    float ss = a.x*a.x + a.y*a.y + a.z*a.z + a.w*a.w
             + b.x*b.x + b.y*b.y + b.z*b.z + b.w*b.w;
    #pragma unroll
    for (int m = 1; m < 64; m <<= 1) ss += __shfl_xor(ss, m);
    const float inv = 1.0f / sqrtf(ss);
    ushort4* dst = (ushort4*)(out + (size_t)row * DIM);
    ushort4 o;
    o.x = f2bf(a.x*inv); o.y = f2bf(a.y*inv); o.z = f2bf(a.z*inv); o.w = f2bf(a.w*inv);
    dst[lane] = o;
    o.x = f2bf(b.x*inv); o.y = f2bf(b.y*inv); o.z = f2bf(b.z*inv); o.w = f2bf(b.w*inv);
    dst[lane + 64] = o;
}

// ---------------- Kernel 2: 256x256 tile, BK=64 (8 convoys), atomic-free epilogue -----
// R9 structure with BK doubled 32->64: 8 barrier convoys instead of 16, double
// MFMA per convoy. LDS 2 bufs x 2 ops x [256 rows x 64 ushort] = 128 KB
// (1 block/CU already -> no occupancy loss). Staging/ds_read = R1's proven
// 128B-row geometry (0 conflicts measured): stored(r,g) = data(r, g^(r&7)),
// linear gload_lds dest + inverse-swizzled source + XOR'd ds_read.
// NOTE (R12 lesson): NO min-waves launch_bounds -- 128 regs/lane caps at
// 16 waves/CU; demanding more spills the AGPR accumulator to scratch.
__global__ __launch_bounds__(1024, 1) void kgemm(const unsigned short* __restrict__ E,
                                                 float* __restrict__ part,
                                                 float* __restrict__ pospart) {
    __shared__ unsigned short lds[2][2][256 * 64];   // [buf][A/B][256 rows x 128 B]

    const int tid = threadIdx.x;
    const int w = tid >> 6;          // 0..15
    const int l = tid & 63;

    // ---- block id -> (bi, bj): supertile triangle decode ----
    const int lin = (int)((blockIdx.x & 7) * 66 + (blockIdx.x >> 3));
    int rem = lin;
    int SI = -1, SJ = -1;
    #pragma unroll
    for (int s = 0; s < 10; s++) {
        constexpr int si_t[10] = {0,0,0,0,1,1,1,2,2,3};
        constexpr int sj_t[10] = {0,1,2,3,1,2,3,2,3,3};
        const int sz = (si_t[s] == sj_t[s]) ? 36 : 64;
        if (SI < 0) {
            if (rem < sz) { SI = si_t[s]; SJ = sj_t[s]; }
            else rem -= sz;
        }
    }
    int bi, bj;
    if (SI == SJ) {
        int x = 0;
        while (rem >= 8 - x) { rem -= 8 - x; x++; }
        bi = (SI << 3) + x; bj = (SI << 3) + x + rem;
    } else {
        bi = (SI << 3) + (rem >> 3);
        bj = (SJ << 3) + (rem & 7);
    }

    const int brow = bi << 8;
    const int bcol = bj << 8;
    const int wr = (w >> 2) << 6;        // 0,64,128,192
    const int wc = (w & 3) << 6;         // 0,64,128,192

    f32x4 acc[4][4];
    #pragma unroll
    for (int i = 0; i < 4; i++)
        #pragma unroll
        for (int j = 0; j < 4; j++) acc[i][j] = (f32x4)0.0f;

    // staging: wave w covers rows w*16 + q*8 + (l>>3); source group inverse-swizzled
    const int g_src = (l & 7) ^ (l >> 3);

    auto STAGE = [&](int buf, int kt) {
        const size_t colb = (size_t)((kt << 6) + (g_src << 3));
        #pragma unroll
        for (int q = 0; q < 2; q++) {
            const int rb = (w << 4) + (q << 3);              // wave-uniform row base
            const int r  = rb + (l >> 3);                    // this lane's source row
            gload16(E + (size_t)(brow + r) * DIM + colb, &lds[buf][0][rb << 6]);
            gload16(E + (size_t)(bcol + r) * DIM + colb, &lds[buf][1][rb << 6]);
        }
    };

    auto COMPUTE = [&](int buf) {
        const unsigned short* sA = lds[buf][0];
        const unsigned short* sB = lds[buf][1];
        #pragma unroll
        for (int kk = 0; kk < 2; kk++) {
            bf16x8 aF[4], bF[4];
            const int gk  = (kk << 2) + (l >> 4);            // data 16B-group 0..7
            const int gsw = (gk ^ (l & 7)) << 3;             // swizzled ushort offset
            #pragma unroll
            for (int mi = 0; mi < 4; mi++) {
                const int rr = wr + (mi << 4) + (l & 15);
                aF[mi] = *(const bf16x8*)&sA[(rr << 6) + gsw];
            }
            #pragma unroll
            for (int ni = 0; ni < 4; ni++) {
                const int rr = wc + (ni << 4) + (l & 15);
                bF[ni] = *(const bf16x8*)&sB[(rr << 6) + gsw];
            }
            #pragma unroll
            for (int mi = 0; mi < 4; mi++)
                #pragma unroll
                for (int ni = 0; ni < 4; ni++)
                    acc[mi][ni] = __builtin_amdgcn_mfma_f32_16x16x32_bf16(
                        aF[mi], bF[ni], acc[mi][ni], 0, 0, 0);
        }
    };

    STAGE(0, 0);
    #pragma unroll
    for (int kt = 0; kt < 8; kt++) {
        if (kt > 0) __builtin_amdgcn_s_barrier();            // prev buffer free
        if (kt < 7) {
            STAGE((kt + 1) & 1, kt + 1);                     // prefetch next (4 loads)
            asm volatile("s_waitcnt vmcnt(4)" ::: "memory"); // cur tile landed
        } else {
            asm volatile("s_waitcnt vmcnt(0)" ::: "memory");
        }
        __builtin_amdgcn_sched_barrier(0);
        __builtin_amdgcn_s_barrier();                        // cur tile ready
        COMPUTE(kt & 1);
    }

    // ---- epilogue: exp(10*dot - 10), classify, LDS assemble, streaming store ----
    float* lds_row = (float*)&lds[0][0][0];       // [4][256]
    float* lds_col = lds_row + 1024;              // [4][256]
    float* lds_pos = lds_row + 2048;              // [4][256]

    __syncthreads();   // all COMPUTE reads done before LDS reuse

    if (bi == bj) {
        #pragma unroll
        for (int mi = 0; mi < 4; mi++) {
            #pragma unroll
            for (int r = 0; r < 4; r++) {
                const int lrow = wr + (mi << 4) + ((l >> 4) << 2) + r;
                const int gi = brow + lrow;
                float p = 0.0f, n = 0.0f;
                #pragma unroll
                for (int ni = 0; ni < 4; ni++) {
                    const int gj = bcol + wc + (ni << 4) + (l & 15);
                    const float e = __expf(fmaf(acc[mi][ni][r], 10.0f, -10.0f));
                    if (gi == gj) {
                    } else if ((gi >> 2) == (gj >> 2)) {
                        p += e;
                    } else {
                        n += e;
                    }
                }
                #pragma unroll
                for (int m = 1; m < 16; m <<= 1) {
                    n += __shfl_xor(n, m);
                    p += __shfl_xor(p, m);
                }
                if ((l & 15) == 0) {
                    lds_row[((w & 3) << 8) + lrow] = n;
                    lds_pos[((w & 3) << 8) + lrow] = p;
                }
            }
        }
    } else {
        float c[4] = {0.0f, 0.0f, 0.0f, 0.0f};
        #pragma unroll
        for (int mi = 0; mi < 4; mi++) {
            #pragma unroll
            for (int r = 0; r < 4; r++) {
                const int lrow = wr + (mi << 4) + ((l >> 4) << 2) + r;
                float n = 0.0f;
                #pragma unroll
                for (int ni = 0; ni < 4; ni++) {
                    const float e = __expf(fmaf(acc[mi][ni][r], 10.0f, -10.0f));
                    n += e;
                    c[ni] += e;
                }
                #pragma unroll
                for (int m = 1; m < 16; m <<= 1) n += __shfl_xor(n, m);
                if ((l & 15) == 0) lds_row[((w & 3) << 8) + lrow] = n;
            }
        }
        #pragma unroll
        for (int ni = 0; ni < 4; ni++) {
            c[ni] += __shfl_xor(c[ni], 16);
            c[ni] += __shfl_xor(c[ni], 32);
            if ((l >> 4) == 0)
                lds_col[((w >> 2) << 8) + wc + (ni << 4) + l] = c[ni];
        }
    }
    __syncthreads();

    if (tid < 256) {
        const float s = lds_row[tid] + lds_row[256 + tid]
                      + lds_row[512 + tid] + lds_row[768 + tid];
        part[((size_t)lin << 9) + tid] = s;
    } else if (tid < 512) {
        if (bi != bj) {
            const int cc = tid - 256;
            const float s = lds_col[cc] + lds_col[256 + cc]
                          + lds_col[512 + cc] + lds_col[768 + cc];
            part[((size_t)lin << 9) + 256 + cc] = s;
        }
    } else if (tid < 768) {
        if (bi == bj) {
            const int rr = tid - 512;
            const float s = lds_pos[rr] + lds_pos[256 + rr]
                          + lds_pos[512 + rr] + lds_pos[768 + rr];
            pospart[(bi << 8) + rr] = s;
        }
    }
}

// ---------------- Kernel 3: gather partials, compute loss, reduce ----------------
__global__ __launch_bounds__(256) void kred(const float* __restrict__ part,
                                            const float* __restrict__ pospart,
                                            float* __restrict__ out) {
    const int T = blockIdx.x;
    const int r = threadIdx.x;

    auto linof = [](int a, int b) {   // a <= b, 0..31
        constexpr int base[4][4] = {{0, 36, 100, 164},
                                    {0, 228, 264, 328},
                                    {0, 0, 392, 428},
                                    {0, 0, 0, 492}};
        const int SI = a >> 3, SJ = b >> 3, x = a & 7, y = b & 7;
        int inner;
        if (SI == SJ) inner = (x << 3) - ((x * (x - 1)) >> 1) + (y - x);
        else          inner = (x << 3) + y;
        return base[SI][SJ] + inner;
    };

    float n = 0.0f;
    for (int bj = T; bj < 32; bj++)
        n += part[((size_t)linof(T, bj) << 9) + r];
    for (int bi = 0; bi < T; bi++)
        n += part[((size_t)linof(bi, T) << 9) + 256 + r];
    const float p = pospart[(T << 8) + r];

    float s = __logf(p + n + 1e-8f) - __logf(p);
    #pragma unroll
    for (int m = 1; m < 64; m <<= 1) s += __shfl_xor(s, m);
    __shared__ float red[4];
    if ((r & 63) == 0) red[r >> 6] = s;
    __syncthreads();
    if (r == 0)
        atomicAdd(out, (red[0] + red[1] + red[2] + red[3]) * (1.0f / (float)NROWS));
}

extern "C" void kernel_launch(void* const* d_in, const int* in_sizes, int n_in,
                              void* d_out, int out_size, void* d_ws, size_t ws_size,
                              hipStream_t stream) {
    (void)in_sizes; (void)n_in; (void)out_size; (void)ws_size;
    const float* emb = (const float*)d_in[0];
    unsigned short* En = (unsigned short*)d_ws;                          // 8 MB bf16
    float* pospart = (float*)((char*)d_ws + (size_t)NROWS * DIM * 2);    // 32 KB
    float* part    = pospart + 32 * 256;                                 // 1.05 MB

    knorm<<<NROWS / 4, 256, 0, stream>>>(emb, En, (float*)d_out);
    kgemm<<<528, 1024, 0, stream>>>(En, part, pospart);
    kred<<<32, 256, 0, stream>>>(part, pospart, (float*)d_out);
}

// Round 15
// 74.784 us; speedup vs baseline: 6.7601x; 1.0360x over previous
//
#include <hip/hip_runtime.h>
#include <hip/hip_bf16.h>
#include <stdint.h>

#define NROWS 8192
#define DIM 512

typedef short bf16x8 __attribute__((ext_vector_type(8)));
typedef float f32x4 __attribute__((ext_vector_type(4)));

__device__ __forceinline__ unsigned short f2bf(float f) {
    union { float f; uint32_t u; } c; c.f = f;
    uint32_t u = c.u;
    return (unsigned short)((u + 0x7FFFu + ((u >> 16) & 1u)) >> 16);
}

__device__ __forceinline__ void gload16(const unsigned short* g, unsigned short* l) {
    __builtin_amdgcn_global_load_lds((const __attribute__((address_space(1))) void*)g,
                                     (__attribute__((address_space(3))) void*)l,
                                     16, 0, 0);
}

// ---------------- Kernel 1: L2-normalize rows -> bf16; zero out[0] + split-lin slots --
__global__ __launch_bounds__(256) void knorm(const float* __restrict__ in,
                                             unsigned short* __restrict__ out,
                                             float* __restrict__ part,
                                             float* __restrict__ loss_out) {
    if (blockIdx.x == 0 && threadIdx.x == 0) loss_out[0] = 0.0f;
    if (blockIdx.x < 16) {   // zero the 16 split-tile partial slots (quarters atomicAdd)
        part[((164 + blockIdx.x) << 9) + threadIdx.x] = 0.0f;
        part[((164 + blockIdx.x) << 9) + 256 + threadIdx.x] = 0.0f;
    }
    const int row  = (blockIdx.x << 2) + (threadIdx.x >> 6);
    const int lane = threadIdx.x & 63;
    const float4* src = (const float4*)(in + (size_t)row * DIM);
    float4 a = src[lane];
    float4 b = src[lane + 64];
    float ss = a.x*a.x + a.y*a.y + a.z*a.z + a.w*a.w
             + b.x*b.x + b.y*b.y + b.z*b.z + b.w*b.w;
    #pragma unroll
    for (int m = 1; m < 64; m <<= 1) ss += __shfl_xor(ss, m);
    const float inv = 1.0f / sqrtf(ss);
    ushort4* dst = (ushort4*)(out + (size_t)row * DIM);
    ushort4 o;
    o.x = f2bf(a.x*inv); o.y = f2bf(a.y*inv); o.z = f2bf(a.z*inv); o.w = f2bf(a.w*inv);
    dst[lane] = o;
    o.x = f2bf(b.x*inv); o.y = f2bf(b.y*inv); o.z = f2bf(b.z*inv); o.w = f2bf(b.w*inv);
    dst[lane + 64] = o;
}

// ---------------- Kernel 2: tail-balanced grid: 512 full 256^2 tiles + 64 quarters -----
// blockIdx: xcd = id&7, slot = id>>3 (0..71). slot<64 -> full tile, lin = xcd*64+slot
// (+16 skip over split set). slot>=64 -> quarter q = xcd*8+(slot-64): parent
// p=q>>2 -> lin=164+p (supertile (0,3), all off-diagonal), quadrant (q>>1&1, q&1).
// Full path = R13 verbatim (BK=64, 8 convoys, counted vmcnt(4), proven swizzle,
// streaming-store partials). Quarter path = R1's proven 128^2 4-wave geometry
// (waves 4..15 idle through barriers); accumulates into part[lin] via atomicAdd
// (33K atomics total; slots pre-zeroed in knorm). 512 heavy blocks = exactly
// 2 rounds; 64 light blocks (T/4) fill the former 16-block 3rd round.
__global__ __launch_bounds__(1024, 1) void kgemm(const unsigned short* __restrict__ E,
                                                 float* __restrict__ part,
                                                 float* __restrict__ pospart) {
    __shared__ unsigned short lds[2][2][256 * 64];   // full: 256 rows; quarter uses first 128

    const int tid = threadIdx.x;
    const int w = tid >> 6;          // 0..15
    const int l = tid & 63;
    const int xcd  = blockIdx.x & 7;
    const int slot = blockIdx.x >> 3;
    const int g_src = (l & 7) ^ (l >> 3);   // inverse-swizzled source 16B-group

    if (slot >= 64) {
        // ================= QUARTER: 128x128 pure-negative, 4 active waves ============
        const int q  = (xcd << 3) + (slot - 64);     // 0..63
        const int p  = q >> 2;                       // parent 0..15
        const int lin = 164 + p;
        const int bi = p >> 3, bj = 24 + (p & 7);
        const int brow = (bi << 8) + (((q >> 1) & 1) << 7);
        const int bcol = (bj << 8) + ((q & 1) << 7);
        const int qroff = (((q >> 1) & 1) << 7);     // row offset within parent
        const int qcoff = ((q & 1) << 7);            // col offset within parent
        const int wr = (w >> 1) << 6;                // valid for w<4
        const int wc = (w & 1) << 6;

        f32x4 acc[4][4];
        #pragma unroll
        for (int i = 0; i < 4; i++)
            #pragma unroll
            for (int j = 0; j < 4; j++) acc[i][j] = (f32x4)0.0f;

        auto STAGEQ = [&](int buf, int kt) {
            const size_t colb = (size_t)((kt << 6) + (g_src << 3));
            #pragma unroll
            for (int s = 0; s < 4; s++) {
                const int rb = (w << 5) + (s << 3);          // 0..127 for w<4
                const int r  = rb + (l >> 3);
                gload16(E + (size_t)(brow + r) * DIM + colb, &lds[buf][0][rb << 6]);
                gload16(E + (size_t)(bcol + r) * DIM + colb, &lds[buf][1][rb << 6]);
            }
        };
        auto COMPUTEQ = [&](int buf) {
            const unsigned short* sA = lds[buf][0];
            const unsigned short* sB = lds[buf][1];
            #pragma unroll
            for (int kk = 0; kk < 2; kk++) {
                bf16x8 aF[4], bF[4];
                const int gk  = (kk << 2) + (l >> 4);
                const int gsw = (gk ^ (l & 7)) << 3;
                #pragma unroll
                for (int mi = 0; mi < 4; mi++) {
                    const int rr = wr + (mi << 4) + (l & 15);
                    aF[mi] = *(const bf16x8*)&sA[(rr << 6) + gsw];
                }
                #pragma unroll
                for (int ni = 0; ni < 4; ni++) {
                    const int rr = wc + (ni << 4) + (l & 15);
                    bF[ni] = *(const bf16x8*)&sB[(rr << 6) + gsw];
                }
                #pragma unroll
                for (int mi = 0; mi < 4; mi++)
                    #pragma unroll
                    for (int ni = 0; ni < 4; ni++)
                        acc[mi][ni] = __builtin_amdgcn_mfma_f32_16x16x32_bf16(
                            aF[mi], bF[ni], acc[mi][ni], 0, 0, 0);
            }
        };

        if (w < 4) STAGEQ(0, 0);
        #pragma unroll
        for (int kt = 0; kt < 8; kt++) {
            if (kt > 0) __builtin_amdgcn_s_barrier();
            if (w < 4) {
                if (kt < 7) {
                    STAGEQ((kt + 1) & 1, kt + 1);
                    asm volatile("s_waitcnt vmcnt(8)" ::: "memory");
                } else {
                    asm volatile("s_waitcnt vmcnt(0)" ::: "memory");
                }
            }
            __builtin_amdgcn_sched_barrier(0);
            __builtin_amdgcn_s_barrier();
            if (w < 4) COMPUTEQ(kt & 1);
        }

        if (w < 4) {
            float c[4] = {0.0f, 0.0f, 0.0f, 0.0f};
            #pragma unroll
            for (int mi = 0; mi < 4; mi++) {
                #pragma unroll
                for (int r = 0; r < 4; r++) {
                    const int lrow = wr + (mi << 4) + ((l >> 4) << 2) + r;  // 0..127
                    float n = 0.0f;
                    #pragma unroll
                    for (int ni = 0; ni < 4; ni++) {
                        const float e = __expf(fmaf(acc[mi][ni][r], 10.0f, -10.0f));
                        n += e;
                        c[ni] += e;
                    }
                    #pragma unroll
                    for (int m = 1; m < 16; m <<= 1) n += __shfl_xor(n, m);
                    if ((l & 15) == 0)
                        atomicAdd(&part[((size_t)lin << 9) + qroff + lrow], n);
                }
            }
            #pragma unroll
            for (int ni = 0; ni < 4; ni++) {
                c[ni] += __shfl_xor(c[ni], 16);
                c[ni] += __shfl_xor(c[ni], 32);
                if ((l >> 4) == 0)
                    atomicAdd(&part[((size_t)lin << 9) + 256 + qcoff + wc + (ni << 4) + l],
                              c[ni]);
            }
        }
        return;
    }

    // ================= FULL: 256x256 tile (R13 verbatim) =============================
    const int f   = (xcd << 6) + slot;               // 0..511
    const int lin = f + (f >= 164 ? 16 : 0);         // skip split set 164..179
    int rem = lin;
    int SI = -1, SJ = -1;
    #pragma unroll
    for (int s = 0; s < 10; s++) {
        constexpr int si_t[10] = {0,0,0,0,1,1,1,2,2,3};
        constexpr int sj_t[10] = {0,1,2,3,1,2,3,2,3,3};
        const int sz = (si_t[s] == sj_t[s]) ? 36 : 64;
        if (SI < 0) {
            if (rem < sz) { SI = si_t[s]; SJ = sj_t[s]; }
            else rem -= sz;
        }
    }
    int bi, bj;
    if (SI == SJ) {
        int x = 0;
        while (rem >= 8 - x) { rem -= 8 - x; x++; }
        bi = (SI << 3) + x; bj = (SI << 3) + x + rem;
    } else {
        bi = (SI << 3) + (rem >> 3);
        bj = (SJ << 3) + (rem & 7);
    }

    const int brow = bi << 8;
    const int bcol = bj << 8;
    const int wr = (w >> 2) << 6;
    const int wc = (w & 3) << 6;

    f32x4 acc[4][4];
    #pragma unroll
    for (int i = 0; i < 4; i++)
        #pragma unroll
        for (int j = 0; j < 4; j++) acc[i][j] = (f32x4)0.0f;

    auto STAGE = [&](int buf, int kt) {
        const size_t colb = (size_t)((kt << 6) + (g_src << 3));
        #pragma unroll
        for (int s = 0; s < 2; s++) {
            const int rb = (w << 4) + (s << 3);
            const int r  = rb + (l >> 3);
            gload16(E + (size_t)(brow + r) * DIM + colb, &lds[buf][0][rb << 6]);
            gload16(E + (size_t)(bcol + r) * DIM + colb, &lds[buf][1][rb << 6]);
        }
    };

    auto COMPUTE = [&](int buf) {
        const unsigned short* sA = lds[buf][0];
        const unsigned short* sB = lds[buf][1];
        #pragma unroll
        for (int kk = 0; kk < 2; kk++) {
            bf16x8 aF[4], bF[4];
            const int gk  = (kk << 2) + (l >> 4);
            const int gsw = (gk ^ (l & 7)) << 3;
            #pragma unroll
            for (int mi = 0; mi < 4; mi++) {
                const int rr = wr + (mi << 4) + (l & 15);
                aF[mi] = *(const bf16x8*)&sA[(rr << 6) + gsw];
            }
            #pragma unroll
            for (int ni = 0; ni < 4; ni++) {
                const int rr = wc + (ni << 4) + (l & 15);
                bF[ni] = *(const bf16x8*)&sB[(rr << 6) + gsw];
            }
            #pragma unroll
            for (int mi = 0; mi < 4; mi++)
                #pragma unroll
                for (int ni = 0; ni < 4; ni++)
                    acc[mi][ni] = __builtin_amdgcn_mfma_f32_16x16x32_bf16(
                        aF[mi], bF[ni], acc[mi][ni], 0, 0, 0);
        }
    };

    STAGE(0, 0);
    #pragma unroll
    for (int kt = 0; kt < 8; kt++) {
        if (kt > 0) __builtin_amdgcn_s_barrier();
        if (kt < 7) {
            STAGE((kt + 1) & 1, kt + 1);
            asm volatile("s_waitcnt vmcnt(4)" ::: "memory");
        } else {
            asm volatile("s_waitcnt vmcnt(0)" ::: "memory");
        }
        __builtin_amdgcn_sched_barrier(0);
        __builtin_amdgcn_s_barrier();
        COMPUTE(kt & 1);
    }

    float* lds_row = (float*)&lds[0][0][0];       // [4][256]
    float* lds_col = lds_row + 1024;              // [4][256]
    float* lds_pos = lds_row + 2048;              // [4][256]

    __syncthreads();

    if (bi == bj) {
        #pragma unroll
        for (int mi = 0; mi < 4; mi++) {
            #pragma unroll
            for (int r = 0; r < 4; r++) {
                const int lrow = wr + (mi << 4) + ((l >> 4) << 2) + r;
                const int gi = brow + lrow;
                float p = 0.0f, n = 0.0f;
                #pragma unroll
                for (int ni = 0; ni < 4; ni++) {
                    const int gj = bcol + wc + (ni << 4) + (l & 15);
                    const float e = __expf(fmaf(acc[mi][ni][r], 10.0f, -10.0f));
                    if (gi == gj) {
                    } else if ((gi >> 2) == (gj >> 2)) {
                        p += e;
                    } else {
                        n += e;
                    }
                }
                #pragma unroll
                for (int m = 1; m < 16; m <<= 1) {
                    n += __shfl_xor(n, m);
                    p += __shfl_xor(p, m);
                }
                if ((l & 15) == 0) {
                    lds_row[((w & 3) << 8) + lrow] = n;
                    lds_pos[((w & 3) << 8) + lrow] = p;
                }
            }
        }
    } else {
        float c[4] = {0.0f, 0.0f, 0.0f, 0.0f};
        #pragma unroll
        for (int mi = 0; mi < 4; mi++) {
            #pragma unroll
            for (int r = 0; r < 4; r++) {
                const int lrow = wr + (mi << 4) + ((l >> 4) << 2) + r;
                float n = 0.0f;
                #pragma unroll
                for (int ni = 0; ni < 4; ni++) {
                    const float e = __expf(fmaf(acc[mi][ni][r], 10.0f, -10.0f));
                    n += e;
                    c[ni] += e;
                }
                #pragma unroll
                for (int m = 1; m < 16; m <<= 1) n += __shfl_xor(n, m);
                if ((l & 15) == 0) lds_row[((w & 3) << 8) + lrow] = n;
            }
        }
        #pragma unroll
        for (int ni = 0; ni < 4; ni++) {
            c[ni] += __shfl_xor(c[ni], 16);
            c[ni] += __shfl_xor(c[ni], 32);
            if ((l >> 4) == 0)
                lds_col[((w >> 2) << 8) + wc + (ni << 4) + l] = c[ni];
        }
    }
    __syncthreads();

    if (tid < 256) {
        const float s = lds_row[tid] + lds_row[256 + tid]
                      + lds_row[512 + tid] + lds_row[768 + tid];
        part[((size_t)lin << 9) + tid] = s;
    } else if (tid < 512) {
        if (bi != bj) {
            const int cc = tid - 256;
            const float s = lds_col[cc] + lds_col[256 + cc]
                          + lds_col[512 + cc] + lds_col[768 + cc];
            part[((size_t)lin << 9) + 256 + cc] = s;
        }
    } else if (tid < 768) {
        if (bi == bj) {
            const int rr = tid - 512;
            const float s = lds_pos[rr] + lds_pos[256 + rr]
                          + lds_pos[512 + rr] + lds_pos[768 + rr];
            pospart[(bi << 8) + rr] = s;
        }
    }
}

// ---------------- Kernel 3: gather partials, compute loss, reduce ----------------
__global__ __launch_bounds__(256) void kred(const float* __restrict__ part,
                                            const float* __restrict__ pospart,
                                            float* __restrict__ out) {
    const int T = blockIdx.x;
    const int r = threadIdx.x;

    auto linof = [](int a, int b) {   // a <= b, 0..31
        constexpr int base[4][4] = {{0, 36, 100, 164},
                                    {0, 228, 264, 328},
                                    {0, 0, 392, 428},
                                    {0, 0, 0, 492}};
        const int SI = a >> 3, SJ = b >> 3, x = a & 7, y = b & 7;
        int inner;
        if (SI == SJ) inner = (x << 3) - ((x * (x - 1)) >> 1) + (y - x);
        else          inner = (x << 3) + y;
        return base[SI][SJ] + inner;
    };

    float n = 0.0f;
    for (int bj = T; bj < 32; bj++)
        n += part[((size_t)linof(T, bj) << 9) + r];
    for (int bi = 0; bi < T; bi++)
        n += part[((size_t)linof(bi, T) << 9) + 256 + r];
    const float p = pospart[(T << 8) + r];

    float s = __logf(p + n + 1e-8f) - __logf(p);
    #pragma unroll
    for (int m = 1; m < 64; m <<= 1) s += __shfl_xor(s, m);
    __shared__ float red[4];
    if ((r & 63) == 0) red[r >> 6] = s;
    __syncthreads();
    if (r == 0)
        atomicAdd(out, (red[0] + red[1] + red[2] + red[3]) * (1.0f / (float)NROWS));
}

extern "C" void kernel_launch(void* const* d_in, const int* in_sizes, int n_in,
                              void* d_out, int out_size, void* d_ws, size_t ws_size,
                              hipStream_t stream) {
    (void)in_sizes; (void)n_in; (void)out_size; (void)ws_size;
    const float* emb = (const float*)d_in[0];
    unsigned short* En = (unsigned short*)d_ws;                          // 8 MB bf16
    float* pospart = (float*)((char*)d_ws + (size_t)NROWS * DIM * 2);    // 32 KB
    float* part    = pospart + 32 * 256;                                 // 1.05 MB

    knorm<<<NROWS / 4, 256, 0, stream>>>(emb, En, part, (float*)d_out);
    kgemm<<<576, 1024, 0, stream>>>(En, part, pospart);
    kred<<<32, 256, 0, stream>>>(part, pospart, (float*)d_out);
}